// Round 6
// baseline (17.626 us; speedup 1.0000x reference)
//
#include <hip/hip_runtime.h>

// Soft polygon rasterization (mode=mask), B=128, N=64, W=H=64.
// R6 = R5 + 6-float edge record (b128 + b64 LDS reads, was 2x b128):
//   e0 = {ax, ay, dx, dy}, e1 = {dx/dd, dy/dd}.
//   by eliminated:   by > py  <=>  pay < dy        (by = ay + dy)
//   dx/dy recomputed: dxdy = dxdd * rcp(dydd)      (1 trans + 1 mul, shared)
// LDS pipe/edge 24 -> 20 cyc; VALU 39 -> ~41 instr. Pipes balanced ~4.3 us.
// Rest as R5: 512 blocks x 256 thr, 4 px/thread, ballot-parity on scalar
// pipe, fmed3 clamp, min3 folds, float4 store.

typedef unsigned long long u64;

__global__ __launch_bounds__(256, 2) void softpoly_kernel(
    const float* __restrict__ verts, float* __restrict__ out)
{
    __shared__ float4 e0[64];  // ax, ay, dx, dy
    __shared__ float2 e1[64];  // dx/dd, dy/dd

    const int tid = threadIdx.x;
    const int b   = blockIdx.x >> 2;

    if (tid < 64) {
        const float2* vp = (const float2*)(verts + (b << 7));
        float2 a = vp[tid];
        float2 c = vp[(tid + 1) & 63];
        float dx = c.x - a.x, dy = c.y - a.y;
        float dd = fmaxf(fmaf(dx, dx, dy * dy), 1e-12f);
        float rdd = 1.0f / dd;
        e0[tid] = make_float4(a.x, a.y, dx, dy);
        e1[tid] = make_float2(dx * rdd, dy * rdd);
    }
    __syncthreads();

    const int row = ((blockIdx.x & 3) << 4) + (tid >> 4);  // 0..63
    const float py  = (float)row;
    const float pxb = (float)((tid & 15) << 2);

    float md0 = 1e30f, md1 = 1e30f, md2 = 1e30f, md3 = 1e30f;
    u64 pm0 = 0ull, pm1 = 0ull, pm2 = 0ull, pm3 = 0ull;

    #pragma unroll 4
    for (int n = 0; n < 64; n += 2) {
        const float4 A0 = e0[n];     const float2 A1 = e1[n];
        const float4 B0 = e0[n + 1]; const float2 B1 = e1[n + 1];
        float dA0, dA1, dA2, dA3, dB0, dB1, dB2, dB3;
        {
            float pay  = py - A0.y;
            float pdyr = pay * A1.y;                    // pay * dy/dd
            float xma  = pay * (A1.x * __frcp_rn(A1.y)); // pay * dx/dy
            u64 cm = __ballot(pay < 0.0f) ^ __ballot(pay < A0.w);
            float pax0 = pxb - A0.x, pax1 = pax0 + 1.0f,
                  pax2 = pax0 + 2.0f, pax3 = pax0 + 3.0f;
            float t0 = __builtin_amdgcn_fmed3f(fmaf(pax0, A1.x, pdyr), 0.f, 1.f);
            float t1 = __builtin_amdgcn_fmed3f(fmaf(pax1, A1.x, pdyr), 0.f, 1.f);
            float t2 = __builtin_amdgcn_fmed3f(fmaf(pax2, A1.x, pdyr), 0.f, 1.f);
            float t3 = __builtin_amdgcn_fmed3f(fmaf(pax3, A1.x, pdyr), 0.f, 1.f);
            float ex0 = fmaf(-t0, A0.z, pax0), ey0 = fmaf(-t0, A0.w, pay);
            float ex1 = fmaf(-t1, A0.z, pax1), ey1 = fmaf(-t1, A0.w, pay);
            float ex2 = fmaf(-t2, A0.z, pax2), ey2 = fmaf(-t2, A0.w, pay);
            float ex3 = fmaf(-t3, A0.z, pax3), ey3 = fmaf(-t3, A0.w, pay);
            dA0 = fmaf(ex0, ex0, ey0 * ey0);
            dA1 = fmaf(ex1, ex1, ey1 * ey1);
            dA2 = fmaf(ex2, ex2, ey2 * ey2);
            dA3 = fmaf(ex3, ex3, ey3 * ey3);
            pm0 ^= cm & __ballot(pax0 < xma);
            pm1 ^= cm & __ballot(pax1 < xma);
            pm2 ^= cm & __ballot(pax2 < xma);
            pm3 ^= cm & __ballot(pax3 < xma);
        }
        {
            float pay  = py - B0.y;
            float pdyr = pay * B1.y;
            float xma  = pay * (B1.x * __frcp_rn(B1.y));
            u64 cm = __ballot(pay < 0.0f) ^ __ballot(pay < B0.w);
            float pax0 = pxb - B0.x, pax1 = pax0 + 1.0f,
                  pax2 = pax0 + 2.0f, pax3 = pax0 + 3.0f;
            float t0 = __builtin_amdgcn_fmed3f(fmaf(pax0, B1.x, pdyr), 0.f, 1.f);
            float t1 = __builtin_amdgcn_fmed3f(fmaf(pax1, B1.x, pdyr), 0.f, 1.f);
            float t2 = __builtin_amdgcn_fmed3f(fmaf(pax2, B1.x, pdyr), 0.f, 1.f);
            float t3 = __builtin_amdgcn_fmed3f(fmaf(pax3, B1.x, pdyr), 0.f, 1.f);
            float ex0 = fmaf(-t0, B0.z, pax0), ey0 = fmaf(-t0, B0.w, pay);
            float ex1 = fmaf(-t1, B0.z, pax1), ey1 = fmaf(-t1, B0.w, pay);
            float ex2 = fmaf(-t2, B0.z, pax2), ey2 = fmaf(-t2, B0.w, pay);
            float ex3 = fmaf(-t3, B0.z, pax3), ey3 = fmaf(-t3, B0.w, pay);
            dB0 = fmaf(ex0, ex0, ey0 * ey0);
            dB1 = fmaf(ex1, ex1, ey1 * ey1);
            dB2 = fmaf(ex2, ex2, ey2 * ey2);
            dB3 = fmaf(ex3, ex3, ey3 * ey3);
            pm0 ^= cm & __ballot(pax0 < xma);
            pm1 ^= cm & __ballot(pax1 < xma);
            pm2 ^= cm & __ballot(pax2 < xma);
            pm3 ^= cm & __ballot(pax3 < xma);
        }
        md0 = fminf(md0, fminf(dA0, dB0));  // -> v_min3_f32
        md1 = fminf(md1, fminf(dA1, dB1));
        md2 = fminf(md2, fminf(dA2, dB2));
        md3 = fminf(md3, fminf(dA3, dB3));
    }

    const int lane = tid & 63;
    const float s0 = ((pm0 >> lane) & 1ull) ? 10.0f : -10.0f;
    const float s1 = ((pm1 >> lane) & 1ull) ? 10.0f : -10.0f;
    const float s2 = ((pm2 >> lane) & 1ull) ? 10.0f : -10.0f;
    const float s3 = ((pm3 >> lane) & 1ull) ? 10.0f : -10.0f;
    float4 r;
    r.x = 1.0f / (1.0f + __expf(-s0 * md0));
    r.y = 1.0f / (1.0f + __expf(-s1 * md1));
    r.z = 1.0f / (1.0f + __expf(-s2 * md2));
    r.w = 1.0f / (1.0f + __expf(-s3 * md3));
    ((float4*)out)[(b << 10) + (row << 4) + (tid & 15)] = r;
}

extern "C" void kernel_launch(void* const* d_in, const int* in_sizes, int n_in,
                              void* d_out, int out_size, void* d_ws, size_t ws_size,
                              hipStream_t stream) {
    const float* verts = (const float*)d_in[0];
    float* out = (float*)d_out;
    const int B = out_size >> 12;  // 64*64 px per image
    softpoly_kernel<<<dim3(B * 4), dim3(256), 0, stream>>>(verts, out);
}

// Round 7
// 16.007 us; speedup vs baseline: 1.1011x; 1.1011x over previous
//
#include <hip/hip_runtime.h>

// Soft polygon rasterization (mode=mask), B=128, N=64, W=H=64.
// R7 = R5 geometry + 6-float record + division-free crossing test.
//   e0 = {ax, ay, dx, dy} (b128), e1 = {dx/dd, dy/dd} (b64).
//   crossing: cond && ((pax*dy < pay*dx) ^ (pay<0))   [cross-multiplied,
//     sign(dy) == !(pay<0) whenever cond holds]  -> no rcp/div anywhere.
//   cm  = ballot(pay<0) ^ ballot(pay<dy)   (by>py <=> pay<dy, by=ay+dy)
// 512 blocks x 256 thr, 4 px/thread in-row, float4 store, ballot-parity
// on scalar pipe, fmed3 clamp, pairwise v_min3 folds.
// Pipe model: VALU ~40 instr/edge ~4.3us, LDS 20cyc/edge ~4.3us (balanced).

typedef unsigned long long u64;

__global__ __launch_bounds__(256, 2) void softpoly_kernel(
    const float* __restrict__ verts, float* __restrict__ out)
{
    __shared__ float4 e0[64];  // ax, ay, dx, dy
    __shared__ float2 e1[64];  // dx/dd, dy/dd

    const int tid = threadIdx.x;
    const int b   = blockIdx.x >> 2;

    if (tid < 64) {
        const float2* vp = (const float2*)(verts + (b << 7));
        float2 a = vp[tid];
        float2 c = vp[(tid + 1) & 63];
        float dx = c.x - a.x, dy = c.y - a.y;
        float dd = fmaxf(fmaf(dx, dx, dy * dy), 1e-12f);
        float rdd = 1.0f / dd;
        e0[tid] = make_float4(a.x, a.y, dx, dy);
        e1[tid] = make_float2(dx * rdd, dy * rdd);
    }
    __syncthreads();

    const int row = ((blockIdx.x & 3) << 4) + (tid >> 4);  // 0..63
    const float py  = (float)row;
    const float pxb = (float)((tid & 15) << 2);

    float md0 = 1e30f, md1 = 1e30f, md2 = 1e30f, md3 = 1e30f;
    u64 pm0 = 0ull, pm1 = 0ull, pm2 = 0ull, pm3 = 0ull;

    #pragma unroll 4
    for (int n = 0; n < 64; n += 2) {
        const float4 A0 = e0[n];     const float2 A1 = e1[n];
        const float4 B0 = e0[n + 1]; const float2 B1 = e1[n + 1];
        float dA0, dA1, dA2, dA3, dB0, dB1, dB2, dB3;
        {
            float pay   = py - A0.y;
            float pdyr  = pay * A1.y;        // pay * dy/dd
            float paydx = pay * A0.z;        // pay * dx
            u64 neg = __ballot(pay < 0.0f);
            u64 cm  = neg ^ __ballot(pay < A0.w);
            float pax0 = pxb - A0.x, pax1 = pax0 + 1.0f,
                  pax2 = pax0 + 2.0f, pax3 = pax0 + 3.0f;
            float t0 = __builtin_amdgcn_fmed3f(fmaf(pax0, A1.x, pdyr), 0.f, 1.f);
            float t1 = __builtin_amdgcn_fmed3f(fmaf(pax1, A1.x, pdyr), 0.f, 1.f);
            float t2 = __builtin_amdgcn_fmed3f(fmaf(pax2, A1.x, pdyr), 0.f, 1.f);
            float t3 = __builtin_amdgcn_fmed3f(fmaf(pax3, A1.x, pdyr), 0.f, 1.f);
            float ex0 = fmaf(-t0, A0.z, pax0), ey0 = fmaf(-t0, A0.w, pay);
            float ex1 = fmaf(-t1, A0.z, pax1), ey1 = fmaf(-t1, A0.w, pay);
            float ex2 = fmaf(-t2, A0.z, pax2), ey2 = fmaf(-t2, A0.w, pay);
            float ex3 = fmaf(-t3, A0.z, pax3), ey3 = fmaf(-t3, A0.w, pay);
            dA0 = fmaf(ex0, ex0, ey0 * ey0);
            dA1 = fmaf(ex1, ex1, ey1 * ey1);
            dA2 = fmaf(ex2, ex2, ey2 * ey2);
            dA3 = fmaf(ex3, ex3, ey3 * ey3);
            pm0 ^= cm & (__ballot(pax0 * A0.w < paydx) ^ neg);
            pm1 ^= cm & (__ballot(pax1 * A0.w < paydx) ^ neg);
            pm2 ^= cm & (__ballot(pax2 * A0.w < paydx) ^ neg);
            pm3 ^= cm & (__ballot(pax3 * A0.w < paydx) ^ neg);
        }
        {
            float pay   = py - B0.y;
            float pdyr  = pay * B1.y;
            float paydx = pay * B0.z;
            u64 neg = __ballot(pay < 0.0f);
            u64 cm  = neg ^ __ballot(pay < B0.w);
            float pax0 = pxb - B0.x, pax1 = pax0 + 1.0f,
                  pax2 = pax0 + 2.0f, pax3 = pax0 + 3.0f;
            float t0 = __builtin_amdgcn_fmed3f(fmaf(pax0, B1.x, pdyr), 0.f, 1.f);
            float t1 = __builtin_amdgcn_fmed3f(fmaf(pax1, B1.x, pdyr), 0.f, 1.f);
            float t2 = __builtin_amdgcn_fmed3f(fmaf(pax2, B1.x, pdyr), 0.f, 1.f);
            float t3 = __builtin_amdgcn_fmed3f(fmaf(pax3, B1.x, pdyr), 0.f, 1.f);
            float ex0 = fmaf(-t0, B0.z, pax0), ey0 = fmaf(-t0, B0.w, pay);
            float ex1 = fmaf(-t1, B0.z, pax1), ey1 = fmaf(-t1, B0.w, pay);
            float ex2 = fmaf(-t2, B0.z, pax2), ey2 = fmaf(-t2, B0.w, pay);
            float ex3 = fmaf(-t3, B0.z, pax3), ey3 = fmaf(-t3, B0.w, pay);
            dB0 = fmaf(ex0, ex0, ey0 * ey0);
            dB1 = fmaf(ex1, ex1, ey1 * ey1);
            dB2 = fmaf(ex2, ex2, ey2 * ey2);
            dB3 = fmaf(ex3, ex3, ey3 * ey3);
            pm0 ^= cm & (__ballot(pax0 * B0.w < paydx) ^ neg);
            pm1 ^= cm & (__ballot(pax1 * B0.w < paydx) ^ neg);
            pm2 ^= cm & (__ballot(pax2 * B0.w < paydx) ^ neg);
            pm3 ^= cm & (__ballot(pax3 * B0.w < paydx) ^ neg);
        }
        md0 = fminf(md0, fminf(dA0, dB0));  // -> v_min3_f32
        md1 = fminf(md1, fminf(dA1, dB1));
        md2 = fminf(md2, fminf(dA2, dB2));
        md3 = fminf(md3, fminf(dA3, dB3));
    }

    const int lane = tid & 63;
    const float s0 = ((pm0 >> lane) & 1ull) ? 10.0f : -10.0f;
    const float s1 = ((pm1 >> lane) & 1ull) ? 10.0f : -10.0f;
    const float s2 = ((pm2 >> lane) & 1ull) ? 10.0f : -10.0f;
    const float s3 = ((pm3 >> lane) & 1ull) ? 10.0f : -10.0f;
    float4 r;
    r.x = 1.0f / (1.0f + __expf(-s0 * md0));
    r.y = 1.0f / (1.0f + __expf(-s1 * md1));
    r.z = 1.0f / (1.0f + __expf(-s2 * md2));
    r.w = 1.0f / (1.0f + __expf(-s3 * md3));
    ((float4*)out)[(b << 10) + (row << 4) + (tid & 15)] = r;
}

extern "C" void kernel_launch(void* const* d_in, const int* in_sizes, int n_in,
                              void* d_out, int out_size, void* d_ws, size_t ws_size,
                              hipStream_t stream) {
    const float* verts = (const float*)d_in[0];
    float* out = (float*)d_out;
    const int B = out_size >> 12;  // 64*64 px per image
    softpoly_kernel<<<dim3(B * 4), dim3(256), 0, stream>>>(verts, out);
}

// Round 8
// 15.249 us; speedup vs baseline: 1.1558x; 1.0497x over previous
//
#include <hip/hip_runtime.h>

// Soft polygon rasterization (mode=mask), B=128, N=64, W=H=64.
// R8 = R5 verbatim (best measured: 15.2us) + epilogue-only micros:
//   - sign select via v_cndmask_b32 with parity ballot mask as VOP3 ssrc
//     (the parity bit IS a lane mask) -- replaces 64-bit shift/and/sel chain.
//   - sigmoid reciprocal via v_rcp_f32 (approx, epilogue only).
// Hot loop untouched: 512 blocks x 256 thr, 4 px/thread in-row, 2x b128
// LDS edge records, premultiplied (dx/dd,dy/dd,dx/dy), ballot-parity on
// scalar pipe, fmed3 clamp, pairwise v_min3 folds, float4 store.
// Diagnosis from R5/R6/R7: VALU-bound (~40 instr/edge/thread); LDS cuts
// and packed-math both measured worse.

typedef unsigned long long u64;

__global__ __launch_bounds__(256, 2) void softpoly_kernel(
    const float* __restrict__ verts, float* __restrict__ out)
{
    __shared__ float4 e0[64];  // ax, ay, dx, dy
    __shared__ float4 e1[64];  // dx/dd, dy/dd, dx/dy, by

    const int tid = threadIdx.x;
    const int b   = blockIdx.x >> 2;

    if (tid < 64) {
        const float2* vp = (const float2*)(verts + (b << 7));
        float2 a = vp[tid];
        float2 c = vp[(tid + 1) & 63];
        float dx = c.x - a.x, dy = c.y - a.y;
        float dd = fmaxf(fmaf(dx, dx, dy * dy), 1e-12f);
        float rdd = 1.0f / dd;
        e0[tid] = make_float4(a.x, a.y, dx, dy);
        e1[tid] = make_float4(dx * rdd, dy * rdd, dx / dy, c.y);
    }
    __syncthreads();

    const int row = ((blockIdx.x & 3) << 4) + (tid >> 4);  // 0..63
    const float py  = (float)row;
    const float pxb = (float)((tid & 15) << 2);

    float md0 = 1e30f, md1 = 1e30f, md2 = 1e30f, md3 = 1e30f;
    u64 pm0 = 0ull, pm1 = 0ull, pm2 = 0ull, pm3 = 0ull;

    #pragma unroll 4
    for (int n = 0; n < 64; n += 2) {
        const float4 A0 = e0[n],     A1 = e1[n];
        const float4 B0 = e0[n + 1], B1 = e1[n + 1];
        float dA0, dA1, dA2, dA3, dB0, dB1, dB2, dB3;
        {
            float pay  = py - A0.y;
            float pdyr = pay * A1.y;          // pay * dy/dd
            float xma  = pay * A1.z;          // pay * dx/dy  (vs pax)
            u64 cm = __ballot(A0.y > py) ^ __ballot(A1.w > py);
            float pax0 = pxb - A0.x, pax1 = pax0 + 1.0f,
                  pax2 = pax0 + 2.0f, pax3 = pax0 + 3.0f;
            float t0 = __builtin_amdgcn_fmed3f(fmaf(pax0, A1.x, pdyr), 0.f, 1.f);
            float t1 = __builtin_amdgcn_fmed3f(fmaf(pax1, A1.x, pdyr), 0.f, 1.f);
            float t2 = __builtin_amdgcn_fmed3f(fmaf(pax2, A1.x, pdyr), 0.f, 1.f);
            float t3 = __builtin_amdgcn_fmed3f(fmaf(pax3, A1.x, pdyr), 0.f, 1.f);
            float ex0 = fmaf(-t0, A0.z, pax0), ey0 = fmaf(-t0, A0.w, pay);
            float ex1 = fmaf(-t1, A0.z, pax1), ey1 = fmaf(-t1, A0.w, pay);
            float ex2 = fmaf(-t2, A0.z, pax2), ey2 = fmaf(-t2, A0.w, pay);
            float ex3 = fmaf(-t3, A0.z, pax3), ey3 = fmaf(-t3, A0.w, pay);
            dA0 = fmaf(ex0, ex0, ey0 * ey0);
            dA1 = fmaf(ex1, ex1, ey1 * ey1);
            dA2 = fmaf(ex2, ex2, ey2 * ey2);
            dA3 = fmaf(ex3, ex3, ey3 * ey3);
            pm0 ^= cm & __ballot(pax0 < xma);
            pm1 ^= cm & __ballot(pax1 < xma);
            pm2 ^= cm & __ballot(pax2 < xma);
            pm3 ^= cm & __ballot(pax3 < xma);
        }
        {
            float pay  = py - B0.y;
            float pdyr = pay * B1.y;
            float xma  = pay * B1.z;
            u64 cm = __ballot(B0.y > py) ^ __ballot(B1.w > py);
            float pax0 = pxb - B0.x, pax1 = pax0 + 1.0f,
                  pax2 = pax0 + 2.0f, pax3 = pax0 + 3.0f;
            float t0 = __builtin_amdgcn_fmed3f(fmaf(pax0, B1.x, pdyr), 0.f, 1.f);
            float t1 = __builtin_amdgcn_fmed3f(fmaf(pax1, B1.x, pdyr), 0.f, 1.f);
            float t2 = __builtin_amdgcn_fmed3f(fmaf(pax2, B1.x, pdyr), 0.f, 1.f);
            float t3 = __builtin_amdgcn_fmed3f(fmaf(pax3, B1.x, pdyr), 0.f, 1.f);
            float ex0 = fmaf(-t0, B0.z, pax0), ey0 = fmaf(-t0, B0.w, pay);
            float ex1 = fmaf(-t1, B0.z, pax1), ey1 = fmaf(-t1, B0.w, pay);
            float ex2 = fmaf(-t2, B0.z, pax2), ey2 = fmaf(-t2, B0.w, pay);
            float ex3 = fmaf(-t3, B0.z, pax3), ey3 = fmaf(-t3, B0.w, pay);
            dB0 = fmaf(ex0, ex0, ey0 * ey0);
            dB1 = fmaf(ex1, ex1, ey1 * ey1);
            dB2 = fmaf(ex2, ex2, ey2 * ey2);
            dB3 = fmaf(ex3, ex3, ey3 * ey3);
            pm0 ^= cm & __ballot(pax0 < xma);
            pm1 ^= cm & __ballot(pax1 < xma);
            pm2 ^= cm & __ballot(pax2 < xma);
            pm3 ^= cm & __ballot(pax3 < xma);
        }
        md0 = fminf(md0, fminf(dA0, dB0));  // -> v_min3_f32
        md1 = fminf(md1, fminf(dA1, dB1));
        md2 = fminf(md2, fminf(dA2, dB2));
        md3 = fminf(md3, fminf(dA3, dB3));
    }

    // epilogue: s_k = pm_k-bit ? +10 : -10 via v_cndmask with mask as ssrc
    float vneg = -10.0f, vpos = 10.0f;
    float s0, s1, s2, s3;
    asm("v_cndmask_b32 %0, %1, %2, %3" : "=v"(s0) : "v"(vneg), "v"(vpos), "s"(pm0));
    asm("v_cndmask_b32 %0, %1, %2, %3" : "=v"(s1) : "v"(vneg), "v"(vpos), "s"(pm1));
    asm("v_cndmask_b32 %0, %1, %2, %3" : "=v"(s2) : "v"(vneg), "v"(vpos), "s"(pm2));
    asm("v_cndmask_b32 %0, %1, %2, %3" : "=v"(s3) : "v"(vneg), "v"(vpos), "s"(pm3));
    float4 r;
    r.x = __builtin_amdgcn_rcpf(1.0f + __expf(-s0 * md0));
    r.y = __builtin_amdgcn_rcpf(1.0f + __expf(-s1 * md1));
    r.z = __builtin_amdgcn_rcpf(1.0f + __expf(-s2 * md2));
    r.w = __builtin_amdgcn_rcpf(1.0f + __expf(-s3 * md3));
    ((float4*)out)[(b << 10) + (row << 4) + (tid & 15)] = r;
}

extern "C" void kernel_launch(void* const* d_in, const int* in_sizes, int n_in,
                              void* d_out, int out_size, void* d_ws, size_t ws_size,
                              hipStream_t stream) {
    const float* verts = (const float*)d_in[0];
    float* out = (float*)d_out;
    const int B = out_size >> 12;  // 64*64 px per image
    softpoly_kernel<<<dim3(B * 4), dim3(256), 0, stream>>>(verts, out);
}